// Round 17
// baseline (325.911 us; speedup 1.0000x reference)
//
#include <hip/hip_runtime.h>
#include <hip/hip_bf16.h>
#include <math.h>

#define NB 2        // batch
#define NC 64       // channels
#define ND 8        // head dim (C/8)
#define NN 4096     // tokens (T*W*H)
#define NM 256      // landmarks
#define NL 16       // N/M
#define SCALE 0.35355339059327373f  // 1/sqrt(8)
#define SLICE (NB * NM * NM)        // floats between split-K slices

typedef __attribute__((ext_vector_type(4))) float f32x4;
typedef __attribute__((ext_vector_type(8))) short bf16x8;

__device__ inline ushort f2bf(float f) {
  __hip_bfloat16 h = __float2bfloat16(f);
  return *reinterpret_cast<ushort*>(&h);
}
__device__ inline float bf2f(ushort u) {
  return __uint_as_float(((unsigned int)u) << 16);
}

// async global->LDS, 16B per lane; LDS dest must be wave-linear (base + lane*16)
__device__ inline void gl_lds16(const void* g, void* l) {
  __builtin_amdgcn_global_load_lds(
      (const __attribute__((address_space(1))) unsigned int*)g,
      (__attribute__((address_space(3))) unsigned int*)l, 16, 0, 0);
}

// ---------------- qkv projection, 4 output rows per block + fused landmarks (R12) ----------------
__global__ __launch_bounds__(256) void qkv4_kernel(
    const float* __restrict__ x,
    const float* __restrict__ wq, const float* __restrict__ bq,
    const float* __restrict__ wk, const float* __restrict__ bk,
    const float* __restrict__ wv, const float* __restrict__ bv,
    float* __restrict__ q, float* __restrict__ k, float* __restrict__ v,
    float* __restrict__ ql, float* __restrict__ kl) {
  __shared__ float ws[4][NC];
  int o0 = blockIdx.x * 4;
  int b = blockIdx.z;
  int n0 = blockIdx.y * 1024;
  int t = threadIdx.x;
  {
    int j = t >> 6, c = t & 63;
    int o = o0 + j;
    const float* wrow;
    if (o < ND)          wrow = wq + (size_t)o * NC;
    else if (o < 2 * ND) wrow = wk + (size_t)(o - ND) * NC;
    else                 wrow = wv + (size_t)(o - 2 * ND) * NC;
    ws[j][c] = wrow[c];
  }
  __syncthreads();
  int n = n0 + t * 4;
  float4 acc[4];
  #pragma unroll
  for (int j = 0; j < 4; ++j) {
    int o = o0 + j;
    float bias = (o < ND) ? bq[o] : (o < 2 * ND ? bk[o - ND] : bv[o - 2 * ND]);
    acc[j].x = bias; acc[j].y = bias; acc[j].z = bias; acc[j].w = bias;
  }
  for (int c = 0; c < NC; ++c) {
    float4 xv = *(const float4*)(x + ((size_t)b * NC + c) * NN + n);
    #pragma unroll
    for (int j = 0; j < 4; ++j) {
      float wc = ws[j][c];
      acc[j].x += wc * xv.x; acc[j].y += wc * xv.y;
      acc[j].z += wc * xv.z; acc[j].w += wc * xv.w;
    }
  }
  #pragma unroll
  for (int j = 0; j < 4; ++j) {
    int o = o0 + j;
    if (o < ND) {
      float* qp = q + ((size_t)b * NN + n) * ND + o;
      qp[0] = acc[j].x; qp[8] = acc[j].y; qp[16] = acc[j].z; qp[24] = acc[j].w;
    } else if (o < 2 * ND) {
      float* kp = k + ((size_t)b * NN + n) * ND + (o - ND);
      kp[0] = acc[j].x; kp[8] = acc[j].y; kp[16] = acc[j].z; kp[24] = acc[j].w;
    } else {
      *(float4*)(v + ((size_t)b * NC + (o - 2 * ND)) * NN + n) = acc[j];
    }
    if (o < 2 * ND) {
      float s4 = acc[j].x + acc[j].y + acc[j].z + acc[j].w;
      s4 += __shfl_xor(s4, 1);
      s4 += __shfl_xor(s4, 2);
      if ((t & 3) == 0) {
        int g = n0 / 16 + (t >> 2);
        float* dst = (o < ND) ? ql : kl;
        dst[((size_t)b * NM + g) * ND + (o & 7)] = s4 * (1.0f / 16.0f);
      }
    }
  }
}

// ---------------- merged softmaxes: k1 bf16 / k2 f32 / k3 bf16 row-major (R14) ----------------
__global__ __launch_bounds__(256) void scores_all_kernel(
    const float* __restrict__ q, const float* __restrict__ ql,
    const float* __restrict__ kw, const float* __restrict__ kl,
    ushort* __restrict__ k1bf, float* __restrict__ k2w,
    ushort* __restrict__ k3bf) {
  __shared__ float skl[NM][9];
  __shared__ float wred[4], wsum[4];
  int blk = blockIdx.x;
  int t = threadIdx.x;
  if (blk < 2048 + 128) {
    const float* Q; int R, b, xrow;
    bool isbf;
    if (blk < 2048) { b = blk >> 10; xrow = blk & 1023; Q = q;  R = NN; isbf = true; }
    else { int r = blk - 2048; b = r >> 6; xrow = r & 63; Q = ql; R = NM; isbf = false; }
    for (int i = t; i < NM * ND; i += 256) skl[i >> 3][i & 7] = kl[(size_t)b * NM * ND + i];
    __syncthreads();
    int wave = t >> 6, lane = t & 63;
    int r = xrow * 4 + wave;
    const float* qrow = Q + ((size_t)b * R + r) * ND;
    float qr[ND];
    #pragma unroll
    for (int dd = 0; dd < ND; ++dd) qr[dd] = qrow[dd];
    float sc[4];
    float lmax = -1e30f;
    #pragma unroll
    for (int s = 0; s < 4; ++s) {
      int j = lane + 64 * s;
      float a = 0.f;
      #pragma unroll
      for (int dd = 0; dd < ND; ++dd) a += qr[dd] * skl[j][dd];
      sc[s] = a * SCALE;
      lmax = fmaxf(lmax, sc[s]);
    }
    for (int off = 32; off; off >>= 1) lmax = fmaxf(lmax, __shfl_xor(lmax, off));
    float lsum = 0.f;
    #pragma unroll
    for (int s = 0; s < 4; ++s) { sc[s] = expf(sc[s] - lmax); lsum += sc[s]; }
    for (int off = 32; off; off >>= 1) lsum += __shfl_xor(lsum, off);
    float inv = 1.0f / lsum;
    if (isbf) {
      #pragma unroll
      for (int s = 0; s < 4; ++s)
        k1bf[((size_t)b * R + r) * NM + lane + 64 * s] = f2bf(sc[s] * inv);
    } else {
      #pragma unroll
      for (int s = 0; s < 4; ++s)
        k2w[((size_t)b * R + r) * NM + lane + 64 * s] = sc[s] * inv;
    }
  } else {
    // k3 softmax -> bf16 row-major [M][N]
    int r = blk - 2176;
    int b = r >> 8, i = r & 255;
    float qr[ND];
    #pragma unroll
    for (int dd = 0; dd < ND; ++dd) qr[dd] = ql[((size_t)b * NM + i) * ND + dd];
    float sc[16];
    float lmax = -1e30f;
    #pragma unroll
    for (int s = 0; s < 16; ++s) {
      int n = t + 256 * s;
      const float* kp = kw + ((size_t)b * NN + n) * ND;
      float a = 0.f;
      #pragma unroll
      for (int dd = 0; dd < ND; ++dd) a += qr[dd] * kp[dd];
      sc[s] = a * SCALE;
      lmax = fmaxf(lmax, sc[s]);
    }
    for (int off = 32; off; off >>= 1) lmax = fmaxf(lmax, __shfl_xor(lmax, off));
    if ((t & 63) == 0) wred[t >> 6] = lmax;
    __syncthreads();
    lmax = fmaxf(fmaxf(wred[0], wred[1]), fmaxf(wred[2], wred[3]));
    float lsum = 0.f;
    #pragma unroll
    for (int s = 0; s < 16; ++s) { sc[s] = expf(sc[s] - lmax); lsum += sc[s]; }
    for (int off = 32; off; off >>= 1) lsum += __shfl_xor(lsum, off);
    if ((t & 63) == 0) wsum[t >> 6] = lsum;
    __syncthreads();
    lsum = wsum[0] + wsum[1] + wsum[2] + wsum[3];
    float inv = 1.0f / lsum;
    #pragma unroll
    for (int s = 0; s < 16; ++s)
      k3bf[((size_t)b * NM + i) * NN + t + 256 * s] = f2bf(sc[s] * inv);
  }
}

// ---------------- denom: max column-sum per batch (R5) ----------------
__global__ __launch_bounds__(256) void denom_kernel(const float* __restrict__ k2,
                                                    float* __restrict__ denw) {
  __shared__ float red[256];
  int b = blockIdx.x;
  int t = threadIdx.x;
  float cs = 0.f;
  for (int i = 0; i < NM; ++i) cs += k2[((size_t)b * NM + i) * NM + t];
  red[t] = cs;
  __syncthreads();
  for (int off = 128; off; off >>= 1) {
    if (t < off) red[t] = fmaxf(red[t], red[t + off]);
    __syncthreads();
  }
  if (t == 0) denw[b] = red[0];
}

// ============ NS split-K x8: 1024 blocks/launch (4 per CU), R5 internals ============
// O_slice = s_ab * (A @ B)[K-eighth slice] ; slice 0 additionally += s_a * A_total
// amode: 0 = plain fp32; 1 = oct (sum 8 slices); 2 = virtual V0 = k2^T * dval
// bmode: 1 = oct; 2 = virtual V0
__global__ __launch_bounds__(256) void ns8_kernel(
    const float* __restrict__ A, int amode,
    const float* __restrict__ B, int bmode,
    const float* __restrict__ denw, float* __restrict__ O,
    float s_a, float s_ab) {
  __shared__ float As[32][36];    // [row][k-eighth]
  __shared__ float Bs[32][36];    // [k-eighth][col]
  int t = threadIdx.x;
  int bi = blockIdx.y * 32, bj = blockIdx.x * 32;
  int b = blockIdx.z >> 3, slice = blockIdx.z & 7;
  int k0 = slice * 32;
  size_t bo = (size_t)b * NM * NM;
  float dval = (amode == 2 || bmode == 2) ? 1.0f / fmaxf(denw[0], denw[1]) : 0.f;
  // ---- stage A eighth-panel (32 x 32) ----
  if (amode == 2) {
    int k = t >> 3, rc = (t & 7) * 4;
    float4 v = *(const float4*)(A + bo + (size_t)(k0 + k) * NM + bi + rc);
    As[rc + 0][k] = v.x * dval; As[rc + 1][k] = v.y * dval;
    As[rc + 2][k] = v.z * dval; As[rc + 3][k] = v.w * dval;
  } else {
    int ar = t >> 3, ac = (t & 7) * 4;
    const float* p = A + bo + (size_t)(bi + ar) * NM + k0 + ac;
    float4 v = *(const float4*)p;
    if (amode == 1) {
      #pragma unroll
      for (int s = 1; s < 8; ++s) {
        float4 vs = *(const float4*)(p + (size_t)s * SLICE);
        v.x += vs.x; v.y += vs.y; v.z += vs.z; v.w += vs.w;
      }
    }
    *(float4*)&As[ar][ac] = v;
  }
  // ---- stage B eighth-panel (32 x 32) ----
  if (bmode == 2) {
    int c = t >> 3, kc = (t & 7) * 4;
    float4 v = *(const float4*)(B + bo + (size_t)(bj + c) * NM + k0 + kc);
    Bs[kc + 0][c] = v.x * dval; Bs[kc + 1][c] = v.y * dval;
    Bs[kc + 2][c] = v.z * dval; Bs[kc + 3][c] = v.w * dval;
  } else {
    int bk = t >> 3, bc = (t & 7) * 4;
    const float* p = B + bo + (size_t)(k0 + bk) * NM + bj + bc;
    float4 v = *(const float4*)p;
    if (bmode == 1) {
      #pragma unroll
      for (int s = 1; s < 8; ++s) {
        float4 vs = *(const float4*)(p + (size_t)s * SLICE);
        v.x += vs.x; v.y += vs.y; v.z += vs.z; v.w += vs.w;
      }
    }
    *(float4*)&Bs[bk][bc] = v;
  }
  __syncthreads();
  int tx = t & 15, ty = t >> 4;
  float acc[2][2] = {};
  #pragma unroll 8
  for (int kk = 0; kk < 32; ++kk) {
    float a0 = As[ty * 2][kk], a1 = As[ty * 2 + 1][kk];
    float b0 = Bs[kk][tx * 2], b1 = Bs[kk][tx * 2 + 1];
    acc[0][0] += a0 * b0; acc[0][1] += a0 * b1;
    acc[1][0] += a1 * b0; acc[1][1] += a1 * b1;
  }
  float* Op = O + (size_t)slice * SLICE + bo;
  bool addA = (slice == 0) && (s_a != 0.0f);
  #pragma unroll
  for (int i = 0; i < 2; ++i)
    #pragma unroll
    for (int j = 0; j < 2; ++j) {
      int R = bi + ty * 2 + i, C = bj + tx * 2 + j;
      float r = s_ab * acc[i][j];
      if (addA) {
        float av;
        if (amode == 2) {
          av = A[bo + (size_t)C * NM + R] * dval;
        } else if (amode == 1) {
          size_t o = bo + (size_t)R * NM + C;
          av = 0.f;
          #pragma unroll
          for (int s = 0; s < 8; ++s) av += A[o + (size_t)s * SLICE];
        } else {
          av = A[bo + (size_t)R * NM + C];
        }
        r += s_a * av;
      }
      Op[(size_t)R * NM + C] = r;
    }
}

// ---- NS final launch: V' = 3.25*V - 0.25*V@T2 (A,B octs), full K, bf16^T out ----
__global__ __launch_bounds__(256) void gemm_rk32_wt_oct(
    const float* __restrict__ A, const float* __restrict__ Bm,
    ushort* __restrict__ Vt) {
  int b = blockIdx.z;
  int bi = blockIdx.y * 32, bj = blockIdx.x * 32;
  __shared__ float As[32][260];
  __shared__ float Bs[256][36];
  int t = threadIdx.x;
  const float* Ab = A + (size_t)b * NM * NM;
  const float* Bb = Bm + (size_t)b * NM * NM;
  #pragma unroll
  for (int q = 0; q < 8; ++q) {
    int s = q * 256 + t;
    int ar = s >> 6, ac = (s & 63) * 4;
    const float* pa = Ab + (size_t)(bi + ar) * NM + ac;
    float4 va = *(const float4*)pa;
    #pragma unroll
    for (int sl = 1; sl < 8; ++sl) {
      float4 vs = *(const float4*)(pa + (size_t)sl * SLICE);
      va.x += vs.x; va.y += vs.y; va.z += vs.z; va.w += vs.w;
    }
    *(float4*)&As[ar][ac] = va;
    int br = s >> 3, bc = (s & 7) * 4;
    const float* pb = Bb + (size_t)br * NM + bj + bc;
    float4 vb = *(const float4*)pb;
    #pragma unroll
    for (int sl = 1; sl < 8; ++sl) {
      float4 vs = *(const float4*)(pb + (size_t)sl * SLICE);
      vb.x += vs.x; vb.y += vs.y; vb.z += vs.z; vb.w += vs.w;
    }
    *(float4*)&Bs[br][bc] = vb;
  }
  __syncthreads();
  int tx = t & 15, ty = t >> 4;
  float acc[2][2] = {};
  #pragma unroll 8
  for (int kk = 0; kk < NM; ++kk) {
    float a0 = As[ty * 2][kk], a1 = As[ty * 2 + 1][kk];
    float b0 = Bs[kk][tx * 2], b1 = Bs[kk][tx * 2 + 1];
    acc[0][0] += a0 * b0; acc[0][1] += a0 * b1;
    acc[1][0] += a1 * b0; acc[1][1] += a1 * b1;
  }
  __syncthreads();
  float (*tile)[33] = (float (*)[33])&As[0][0];
  #pragma unroll
  for (int i = 0; i < 2; ++i)
    #pragma unroll
    for (int j = 0; j < 2; ++j) {
      int R = ty * 2 + i, C = tx * 2 + j;
      size_t o = (size_t)(bi + R) * NM + bj + C;
      float a0v = 0.f;
      #pragma unroll
      for (int sl = 0; sl < 8; ++sl) a0v += Ab[o + (size_t)sl * SLICE];
      tile[R][C] = 3.25f * a0v - 0.25f * acc[i][j];
    }
  __syncthreads();
  int rr = t >> 3, m4 = (t & 7) * 4;
  ushort4 u;
  u.x = f2bf(tile[m4 + 0][rr]); u.y = f2bf(tile[m4 + 1][rr]);
  u.z = f2bf(tile[m4 + 2][rr]); u.w = f2bf(tile[m4 + 3][rr]);
  *(ushort4*)(Vt + ((size_t)b * NM + bj + rr) * NM + bi + m4) = u;
}

// ---------------- k3bf [B][NM][NN] bf16 -> k3t [B][NN][NM] bf16 (transpose) ----------------
__global__ __launch_bounds__(256) void cvt_t_kernel(const ushort* __restrict__ k3,
                                                    ushort* __restrict__ k3t) {
  int b = blockIdx.z;
  int n0 = blockIdx.x * 32, m0 = blockIdx.y * 32;
  __shared__ ushort tile[32][33];
  int t = threadIdx.x;
  int r = t >> 3, c4 = (t & 7) * 4;
  ushort4 v = *(const ushort4*)(k3 + ((size_t)b * NM + m0 + r) * NN + n0 + c4);
  tile[c4][r] = v.x; tile[c4 + 1][r] = v.y; tile[c4 + 2][r] = v.z; tile[c4 + 3][r] = v.w;
  __syncthreads();
  ushort4 u;
  u.x = tile[r][c4];     u.y = tile[r][c4 + 1];
  u.z = tile[r][c4 + 2]; u.w = tile[r][c4 + 3];
  *(ushort4*)(k3t + ((size_t)b * NN + n0 + r) * NM + m0 + c4) = u;
}

// ---------------- A = k1 @ Vinv via bf16 MFMA (R5) ----------------
__global__ __launch_bounds__(256) void gemm_a_mfma(
    const ushort* __restrict__ k1bf, const ushort* __restrict__ Vt,
    ushort* __restrict__ Abf) {
  int b = blockIdx.z;
  int bi = blockIdx.y * 128, bj = blockIdx.x * 128;
  __shared__ ushort As[128 * 64];
  __shared__ ushort Bs[128 * 64];
  int t = threadIdx.x;
  int wave = t >> 6, lane = t & 63;
  int wr = wave >> 1, wc = wave & 1;
  const ushort* Ab = k1bf + (size_t)b * NN * NM;
  const ushort* Bb = Vt + (size_t)b * NM * NM;
  f32x4 acc[4][4] = {};
  for (int k0 = 0; k0 < NM; k0 += 64) {
    #pragma unroll
    for (int q = 0; q < 4; ++q) {
      int s = q * 256 + t;
      int r = s >> 3, c = s & 7;
      int cs = (c ^ (r & 7)) << 3;
      gl_lds16(Ab + (size_t)(bi + r) * NM + k0 + cs, As + (size_t)s * 8);
      gl_lds16(Bb + (size_t)(bj + r) * NM + k0 + cs, Bs + (size_t)s * 8);
    }
    __syncthreads();
    #pragma unroll
    for (int kk = 0; kk < 2; ++kk) {
      int koff = kk * 64 + (lane >> 4) * 16;
      bf16x8 af[4], bfv[4];
      #pragma unroll
      for (int mi = 0; mi < 4; ++mi) {
        int row = wr * 64 + mi * 16 + (lane & 15);
        af[mi] = *(const bf16x8*)((const char*)As + row * 128 + (koff ^ ((row & 7) << 4)));
      }
      #pragma unroll
      for (int nj = 0; nj < 4; ++nj) {
        int row = wc * 64 + nj * 16 + (lane & 15);
        bfv[nj] = *(const bf16x8*)((const char*)Bs + row * 128 + (koff ^ ((row & 7) << 4)));
      }
      #pragma unroll
      for (int mi = 0; mi < 4; ++mi)
        #pragma unroll
        for (int nj = 0; nj < 4; ++nj)
          acc[mi][nj] = __builtin_amdgcn_mfma_f32_16x16x32_bf16(af[mi], bfv[nj], acc[mi][nj], 0, 0, 0);
    }
    __syncthreads();
  }
  int col = lane & 15, rbase = (lane >> 4) * 4;
  #pragma unroll
  for (int mi = 0; mi < 4; ++mi)
    #pragma unroll
    for (int nj = 0; nj < 4; ++nj)
      #pragma unroll
      for (int r = 0; r < 4; ++r)
        Abf[((size_t)b * NN + bi + wr * 64 + mi * 16 + rbase + r) * NM
            + bj + wc * 64 + nj * 16 + col] = f2bf(acc[mi][nj][r]);
}

// ---------------- attn = A @ k3 via bf16 MFMA, 128x128 tile, XCD swizzle, nt stores ----------------
__global__ __launch_bounds__(256) void gemm_attn_mfma(
    const ushort* __restrict__ Abf, const ushort* __restrict__ K3T,
    float* __restrict__ attn) {
  int lin = blockIdx.z * 1024 + blockIdx.y * 32 + blockIdx.x;
  int swz = (lin & 7) * 256 + (lin >> 3);
  int b = swz >> 10;
  int rem = swz & 1023;
  int bi = (rem >> 5) * 128, bj = (rem & 31) * 128;
  __shared__ ushort As[128 * 64];
  __shared__ ushort Bs[128 * 64];
  int t = threadIdx.x;
  int wave = t >> 6, lane = t & 63;
  int wr = wave >> 1, wc = wave & 1;
  const ushort* Ab = Abf + (size_t)b * NN * NM;
  const ushort* Bb = K3T + (size_t)b * NN * NM;
  f32x4 acc[4][4] = {};
  for (int k0 = 0; k0 < NM; k0 += 64) {
    #pragma unroll
    for (int q = 0; q < 4; ++q) {
      int s = q * 256 + t;
      int r = s >> 3, c = s & 7;
      int cs = (c ^ (r & 7)) << 3;
      gl_lds16(Ab + (size_t)(bi + r) * NM + k0 + cs, As + (size_t)s * 8);
      gl_lds16(Bb + (size_t)(bj + r) * NM + k0 + cs, Bs + (size_t)s * 8);
    }
    __syncthreads();
    #pragma unroll
    for (int kk = 0; kk < 2; ++kk) {
      int koff = kk * 64 + (lane >> 4) * 16;
      bf16x8 af[4], bfv[4];
      #pragma unroll
      for (int mi = 0; mi < 4; ++mi) {
        int row = wr * 64 + mi * 16 + (lane & 15);
        af[mi] = *(const bf16x8*)((const char*)As + row * 128 + (koff ^ ((row & 7) << 4)));
      }
      #pragma unroll
      for (int nj = 0; nj < 4; ++nj) {
        int row = wc * 64 + nj * 16 + (lane & 15);
        bfv[nj] = *(const bf16x8*)((const char*)Bs + row * 128 + (koff ^ ((row & 7) << 4)));
      }
      #pragma unroll
      for (int mi = 0; mi < 4; ++mi)
        #pragma unroll
        for (int nj = 0; nj < 4; ++nj)
          acc[mi][nj] = __builtin_amdgcn_mfma_f32_16x16x32_bf16(af[mi], bfv[nj], acc[mi][nj], 0, 0, 0);
    }
    __syncthreads();
  }
  int col = lane & 15, rbase = (lane >> 4) * 4;
  #pragma unroll
  for (int mi = 0; mi < 4; ++mi)
    #pragma unroll
    for (int nj = 0; nj < 4; ++nj)
      #pragma unroll
      for (int r = 0; r < 4; ++r)
        __builtin_nontemporal_store(
            acc[mi][nj][r],
            &attn[((size_t)b * NN + bi + wr * 64 + mi * 16 + rbase + r) * NN
                  + bj + wc * 64 + nj * 16 + col]);
}

// ---------------- split-K kv (k3 bf16, atomicAdd into zeroed buffer) ----------------
__global__ __launch_bounds__(256) void kv_kernel(
    const ushort* __restrict__ K3, const float* __restrict__ Vv,
    float* __restrict__ kvout) {
  int b = blockIdx.z, bp = blockIdx.x * 64;
  int j0base = blockIdx.y * (NN / 32);
  __shared__ float Ks[64][33], Vs[64][33];
  int t = threadIdx.x, tx = t & 15, ty = t >> 4;
  int lrow = t >> 2, ljc = (t & 3) * 8;
  float acc[4][4] = {};
  for (int j0 = j0base; j0 < j0base + NN / 32; j0 += 32) {
    bf16x8 a0 = *(const bf16x8*)(K3 + ((size_t)b * NM + bp + lrow) * NN + j0 + ljc);
    float4 v0 = *(const float4*)(Vv + ((size_t)b * NC + lrow) * NN + j0 + ljc);
    float4 v1 = *(const float4*)(Vv + ((size_t)b * NC + lrow) * NN + j0 + ljc + 4);
    #pragma unroll
    for (int e = 0; e < 8; ++e) Ks[lrow][ljc + e] = bf2f((ushort)a0[e]);
    Vs[lrow][ljc + 0] = v0.x; Vs[lrow][ljc + 1] = v0.y; Vs[lrow][ljc + 2] = v0.z; Vs[lrow][ljc + 3] = v0.w;
    Vs[lrow][ljc + 4] = v1.x; Vs[lrow][ljc + 5] = v1.y; Vs[lrow][ljc + 6] = v1.z; Vs[lrow][ljc + 7] = v1.w;
    __syncthreads();
    #pragma unroll
    for (int kk = 0; kk < 32; ++kk) {
      float av_[4], bv_[4];
      #pragma unroll
      for (int i = 0; i < 4; ++i) av_[i] = Ks[(ty << 2) + i][kk];
      #pragma unroll
      for (int j = 0; j < 4; ++j) bv_[j] = Vs[(tx << 2) + j][kk];
      #pragma unroll
      for (int i = 0; i < 4; ++i)
        #pragma unroll
        for (int j = 0; j < 4; ++j) acc[i][j] += av_[i] * bv_[j];
    }
    __syncthreads();
  }
  #pragma unroll
  for (int i = 0; i < 4; ++i)
    #pragma unroll
    for (int j = 0; j < 4; ++j)
      atomicAdd(&kvout[((size_t)b * NM + bp + (ty << 2) + i) * NC + (tx << 2) + j], acc[i][j]);
}

// ---------------- out = gamma*(A@kv) + x  (A in bf16, nt stores) ----------------
__global__ __launch_bounds__(256) void out_kernel(
    const ushort* __restrict__ Abf, const float* __restrict__ kvm,
    const float* __restrict__ x, const float* __restrict__ gamma,
    float* __restrict__ outp) {
  __shared__ float As[32 * 256];
  int blk = blockIdx.x;
  int b = blk / (NN / 32), n0 = (blk % (NN / 32)) * 32;
  int t = threadIdx.x;
  for (int it = 0; it < 32; ++it)
    As[it * 256 + (t ^ (it & 31))] = bf2f(Abf[((size_t)b * NN + n0 + it) * NM + t]);
  __syncthreads();
  int tn = t & 31, cg0 = (t >> 5) * 8;
  float g = gamma[0];
  float acc[8] = {};
  for (int p = 0; p < NM; ++p) {
    float a = As[tn * 256 + (p ^ (tn & 31))];
    float4 kv0 = *(const float4*)(kvm + ((size_t)b * NM + p) * NC + cg0);
    float4 kv1 = *(const float4*)(kvm + ((size_t)b * NM + p) * NC + cg0 + 4);
    acc[0] += a * kv0.x; acc[1] += a * kv0.y; acc[2] += a * kv0.z; acc[3] += a * kv0.w;
    acc[4] += a * kv1.x; acc[5] += a * kv1.y; acc[6] += a * kv1.z; acc[7] += a * kv1.w;
  }
  #pragma unroll
  for (int qd = 0; qd < 8; ++qd) {
    int c = cg0 + qd;
    size_t idx = ((size_t)b * NC + c) * NN + n0 + tn;
    __builtin_nontemporal_store(g * acc[qd] + x[idx], &outp[idx]);
  }
}

extern "C" void kernel_launch(void* const* d_in, const int* in_sizes, int n_in,
                              void* d_out, int out_size, void* d_ws, size_t ws_size,
                              hipStream_t stream) {
  const float* x     = (const float*)d_in[0];
  const float* wq    = (const float*)d_in[1];
  const float* bq    = (const float*)d_in[2];
  const float* wk    = (const float*)d_in[3];
  const float* bk    = (const float*)d_in[4];
  const float* wv    = (const float*)d_in[5];
  const float* bv    = (const float*)d_in[6];
  const float* gamma = (const float*)d_in[7];
  float* outp = (float*)d_out;                       // [B][C][N]
  float* attn = outp + (size_t)NB * NC * NN;         // [B][N][N]
  float* w = (float*)d_ws;

  float* qw   = w;                 // [B][N][D]    65536
  float* kw   = qw + 65536;        // [B][N][D]    65536
  float* vw   = kw + 65536;        // [B][C][N]    524288
  float* qlw  = vw + 524288;       // [B][M][D]    4096
  float* klw  = qlw + 4096;        // [B][M][D]    4096
  float* k1w  = klw + 4096;        // 8 MB region: k1bf (4MB) + k3T (4MB)
  float* k2w  = k1w + 2097152;     // [B][M][M]    131072
  float* k3w  = k2w + 131072;      // k3bf bf16 row-major (4 MB)
  float* Abuf = k3w + 1048576;     // 4 MB region: Abf bf16
  float* nsb  = Abuf + 1048576;    // 4 rotating oct-slots x 8*SLICE
  float* Vtw  = nsb + 4 * 8 * SLICE;  // Vinvt bf16  65536 floats
  float* kvw  = Vtw + 65536;       // [B][M][C]    32768
  float* denw = kvw + 32768;       // [2]
  ushort* k1bf  = (ushort*)k1w;                 // [B][N][M] bf16
  ushort* k3T   = (ushort*)k1w + 2097152;       // [B][N][M] bf16 (k3^T)
  ushort* k3bf  = (ushort*)k3w;                 // [B][M][N] bf16 row-major
  ushort* Abf   = (ushort*)Abuf;                // [B][N][M] bf16
  ushort* Vinvt = (ushort*)Vtw;                 // [B][M][M] bf16 (Vinv^T)
  float* S[4] = {nsb, nsb + 8 * SLICE, nsb + 16 * SLICE, nsb + 24 * SLICE};

  hipMemsetAsync(kvw, 0, (size_t)NB * NM * NC * sizeof(float), stream);
  qkv4_kernel<<<dim3(20, NN / 1024, NB), dim3(256), 0, stream>>>(
      x, wq, bq, wk, bk, wv, bv, qw, kw, vw, qlw, klw);
  scores_all_kernel<<<dim3(2048 + 128 + 512), dim3(256), 0, stream>>>(
      qw, qlw, kw, klw, k1bf, k2w, k3bf);
  denom_kernel<<<dim3(NB), dim3(256), 0, stream>>>(k2w, denw);

  // Newton-Schulz: split-K x8 octs, 1024 blocks/launch (4 per CU), 4 rotating slots.
  dim3 g8(8, 8, 8 * NB);
  // iter 0 (V0 virtual): Z->S0, T1->S1, T2->S2, V'->S3
  ns8_kernel<<<g8, dim3(256), 0, stream>>>(k2w, 0, k2w, 2, denw, S[0], 0.f, 1.f);
  ns8_kernel<<<g8, dim3(256), 0, stream>>>(S[0], 1, S[0], 1, denw, S[1], 7.f, -1.f);
  ns8_kernel<<<g8, dim3(256), 0, stream>>>(S[0], 1, S[1], 1, denw, S[2], 15.f, -1.f);
  ns8_kernel<<<g8, dim3(256), 0, stream>>>(k2w, 2, S[2], 1, denw, S[3], 3.25f, -0.25f);
  int vc = 3;
  for (int it = 1; it < 5; ++it) {
    int zs = (vc + 1) & 3, t1 = (vc + 2) & 3, t2 = (vc + 3) & 3;
    ns8_kernel<<<g8, dim3(256), 0, stream>>>(k2w, 0, S[vc], 1, denw, S[zs], 0.f, 1.f);
    ns8_kernel<<<g8, dim3(256), 0, stream>>>(S[zs], 1, S[zs], 1, denw, S[t1], 7.f, -1.f);
    ns8_kernel<<<g8, dim3(256), 0, stream>>>(S[zs], 1, S[t1], 1, denw, S[t2], 15.f, -1.f);
    ns8_kernel<<<g8, dim3(256), 0, stream>>>(S[vc], 1, S[t2], 1, denw, S[zs], 3.25f, -0.25f);
    vc = zs;
  }
  // iter 5: final V' -> Vinvt bf16 transposed (full-K oct kernel)
  {
    int zs = (vc + 1) & 3, t1 = (vc + 2) & 3, t2 = (vc + 3) & 3;
    ns8_kernel<<<g8, dim3(256), 0, stream>>>(k2w, 0, S[vc], 1, denw, S[zs], 0.f, 1.f);
    ns8_kernel<<<g8, dim3(256), 0, stream>>>(S[zs], 1, S[zs], 1, denw, S[t1], 7.f, -1.f);
    ns8_kernel<<<g8, dim3(256), 0, stream>>>(S[zs], 1, S[t1], 1, denw, S[t2], 15.f, -1.f);
    gemm_rk32_wt_oct<<<dim3(8, 8, NB), dim3(256), 0, stream>>>(S[vc], S[t2], Vinvt);
  }

  cvt_t_kernel<<<dim3(NN / 32, NM / 32, NB), dim3(256), 0, stream>>>(k3bf, k3T);
  gemm_a_mfma<<<dim3(NM / 128, NN / 128, NB), dim3(256), 0, stream>>>(k1bf, Vinvt, Abf);
  gemm_attn_mfma<<<dim3(NN / 128, NN / 128, NB), dim3(256), 0, stream>>>(Abf, k3T, attn);
  kv_kernel<<<dim3(NM / 64, 32, NB), dim3(256), 0, stream>>>(k3bf, vw, kvw);
  out_kernel<<<dim3(NB * NN / 32), dim3(256), 0, stream>>>(Abf, kvw, x, gamma, outp);
}

// Round 18
// 280.589 us; speedup vs baseline: 1.1615x; 1.1615x over previous
//
#include <hip/hip_runtime.h>
#include <hip/hip_bf16.h>
#include <math.h>

#define NB 2        // batch
#define NC 64       // channels
#define ND 8        // head dim (C/8)
#define NN 4096     // tokens (T*W*H)
#define NM 256      // landmarks
#define NL 16       // N/M
#define SCALE 0.35355339059327373f  // 1/sqrt(8)
#define SLICE (NB * NM * NM)        // floats between split-K slices

typedef __attribute__((ext_vector_type(4))) float f32x4;
typedef __attribute__((ext_vector_type(8))) short bf16x8;

__device__ inline ushort f2bf(float f) {
  __hip_bfloat16 h = __float2bfloat16(f);
  return *reinterpret_cast<ushort*>(&h);
}
__device__ inline float bf2f(ushort u) {
  return __uint_as_float(((unsigned int)u) << 16);
}

// async global->LDS, 16B per lane; LDS dest must be wave-linear (base + lane*16)
__device__ inline void gl_lds16(const void* g, void* l) {
  __builtin_amdgcn_global_load_lds(
      (const __attribute__((address_space(1))) unsigned int*)g,
      (__attribute__((address_space(3))) unsigned int*)l, 16, 0, 0);
}

// ---------------- qkv projection, 4 output rows per block + fused landmarks (R12) ----------------
__global__ __launch_bounds__(256) void qkv4_kernel(
    const float* __restrict__ x,
    const float* __restrict__ wq, const float* __restrict__ bq,
    const float* __restrict__ wk, const float* __restrict__ bk,
    const float* __restrict__ wv, const float* __restrict__ bv,
    float* __restrict__ q, float* __restrict__ k, float* __restrict__ v,
    float* __restrict__ ql, float* __restrict__ kl) {
  __shared__ float ws[4][NC];
  int o0 = blockIdx.x * 4;
  int b = blockIdx.z;
  int n0 = blockIdx.y * 1024;
  int t = threadIdx.x;
  {
    int j = t >> 6, c = t & 63;
    int o = o0 + j;
    const float* wrow;
    if (o < ND)          wrow = wq + (size_t)o * NC;
    else if (o < 2 * ND) wrow = wk + (size_t)(o - ND) * NC;
    else                 wrow = wv + (size_t)(o - 2 * ND) * NC;
    ws[j][c] = wrow[c];
  }
  __syncthreads();
  int n = n0 + t * 4;
  float4 acc[4];
  #pragma unroll
  for (int j = 0; j < 4; ++j) {
    int o = o0 + j;
    float bias = (o < ND) ? bq[o] : (o < 2 * ND ? bk[o - ND] : bv[o - 2 * ND]);
    acc[j].x = bias; acc[j].y = bias; acc[j].z = bias; acc[j].w = bias;
  }
  for (int c = 0; c < NC; ++c) {
    float4 xv = *(const float4*)(x + ((size_t)b * NC + c) * NN + n);
    #pragma unroll
    for (int j = 0; j < 4; ++j) {
      float wc = ws[j][c];
      acc[j].x += wc * xv.x; acc[j].y += wc * xv.y;
      acc[j].z += wc * xv.z; acc[j].w += wc * xv.w;
    }
  }
  #pragma unroll
  for (int j = 0; j < 4; ++j) {
    int o = o0 + j;
    if (o < ND) {
      float* qp = q + ((size_t)b * NN + n) * ND + o;
      qp[0] = acc[j].x; qp[8] = acc[j].y; qp[16] = acc[j].z; qp[24] = acc[j].w;
    } else if (o < 2 * ND) {
      float* kp = k + ((size_t)b * NN + n) * ND + (o - ND);
      kp[0] = acc[j].x; kp[8] = acc[j].y; kp[16] = acc[j].z; kp[24] = acc[j].w;
    } else {
      *(float4*)(v + ((size_t)b * NC + (o - 2 * ND)) * NN + n) = acc[j];
    }
    if (o < 2 * ND) {
      float s4 = acc[j].x + acc[j].y + acc[j].z + acc[j].w;
      s4 += __shfl_xor(s4, 1);
      s4 += __shfl_xor(s4, 2);
      if ((t & 3) == 0) {
        int g = n0 / 16 + (t >> 2);
        float* dst = (o < ND) ? ql : kl;
        dst[((size_t)b * NM + g) * ND + (o & 7)] = s4 * (1.0f / 16.0f);
      }
    }
  }
}

// ---------------- merged softmaxes: k1 bf16 / k2 f32 / k3 bf16 row-major (R14) ----------------
__global__ __launch_bounds__(256) void scores_all_kernel(
    const float* __restrict__ q, const float* __restrict__ ql,
    const float* __restrict__ kw, const float* __restrict__ kl,
    ushort* __restrict__ k1bf, float* __restrict__ k2w,
    ushort* __restrict__ k3bf) {
  __shared__ float skl[NM][9];
  __shared__ float wred[4], wsum[4];
  int blk = blockIdx.x;
  int t = threadIdx.x;
  if (blk < 2048 + 128) {
    const float* Q; int R, b, xrow;
    bool isbf;
    if (blk < 2048) { b = blk >> 10; xrow = blk & 1023; Q = q;  R = NN; isbf = true; }
    else { int r = blk - 2048; b = r >> 6; xrow = r & 63; Q = ql; R = NM; isbf = false; }
    for (int i = t; i < NM * ND; i += 256) skl[i >> 3][i & 7] = kl[(size_t)b * NM * ND + i];
    __syncthreads();
    int wave = t >> 6, lane = t & 63;
    int r = xrow * 4 + wave;
    const float* qrow = Q + ((size_t)b * R + r) * ND;
    float qr[ND];
    #pragma unroll
    for (int dd = 0; dd < ND; ++dd) qr[dd] = qrow[dd];
    float sc[4];
    float lmax = -1e30f;
    #pragma unroll
    for (int s = 0; s < 4; ++s) {
      int j = lane + 64 * s;
      float a = 0.f;
      #pragma unroll
      for (int dd = 0; dd < ND; ++dd) a += qr[dd] * skl[j][dd];
      sc[s] = a * SCALE;
      lmax = fmaxf(lmax, sc[s]);
    }
    for (int off = 32; off; off >>= 1) lmax = fmaxf(lmax, __shfl_xor(lmax, off));
    float lsum = 0.f;
    #pragma unroll
    for (int s = 0; s < 4; ++s) { sc[s] = expf(sc[s] - lmax); lsum += sc[s]; }
    for (int off = 32; off; off >>= 1) lsum += __shfl_xor(lsum, off);
    float inv = 1.0f / lsum;
    if (isbf) {
      #pragma unroll
      for (int s = 0; s < 4; ++s)
        k1bf[((size_t)b * R + r) * NM + lane + 64 * s] = f2bf(sc[s] * inv);
    } else {
      #pragma unroll
      for (int s = 0; s < 4; ++s)
        k2w[((size_t)b * R + r) * NM + lane + 64 * s] = sc[s] * inv;
    }
  } else {
    // k3 softmax -> bf16 row-major [M][N]
    int r = blk - 2176;
    int b = r >> 8, i = r & 255;
    float qr[ND];
    #pragma unroll
    for (int dd = 0; dd < ND; ++dd) qr[dd] = ql[((size_t)b * NM + i) * ND + dd];
    float sc[16];
    float lmax = -1e30f;
    #pragma unroll
    for (int s = 0; s < 16; ++s) {
      int n = t + 256 * s;
      const float* kp = kw + ((size_t)b * NN + n) * ND;
      float a = 0.f;
      #pragma unroll
      for (int dd = 0; dd < ND; ++dd) a += qr[dd] * kp[dd];
      sc[s] = a * SCALE;
      lmax = fmaxf(lmax, sc[s]);
    }
    for (int off = 32; off; off >>= 1) lmax = fmaxf(lmax, __shfl_xor(lmax, off));
    if ((t & 63) == 0) wred[t >> 6] = lmax;
    __syncthreads();
    lmax = fmaxf(fmaxf(wred[0], wred[1]), fmaxf(wred[2], wred[3]));
    float lsum = 0.f;
    #pragma unroll
    for (int s = 0; s < 16; ++s) { sc[s] = expf(sc[s] - lmax); lsum += sc[s]; }
    for (int off = 32; off; off >>= 1) lsum += __shfl_xor(lsum, off);
    if ((t & 63) == 0) wsum[t >> 6] = lsum;
    __syncthreads();
    lsum = wsum[0] + wsum[1] + wsum[2] + wsum[3];
    float inv = 1.0f / lsum;
    #pragma unroll
    for (int s = 0; s < 16; ++s)
      k3bf[((size_t)b * NM + i) * NN + t + 256 * s] = f2bf(sc[s] * inv);
  }
}

// ---------------- denom: max column-sum per batch (R5) ----------------
__global__ __launch_bounds__(256) void denom_kernel(const float* __restrict__ k2,
                                                    float* __restrict__ denw) {
  __shared__ float red[256];
  int b = blockIdx.x;
  int t = threadIdx.x;
  float cs = 0.f;
  for (int i = 0; i < NM; ++i) cs += k2[((size_t)b * NM + i) * NM + t];
  red[t] = cs;
  __syncthreads();
  for (int off = 128; off; off >>= 1) {
    if (t < off) red[t] = fmaxf(red[t], red[t + off]);
    __syncthreads();
  }
  if (t == 0) denw[b] = red[0];
}

// ============ NS split-K x4: 1024 blocks/launch (2 per CU), R5 internals ============
// O_slice = s_ab * (A @ B)[K-quarter slice] ; slice 0 additionally += s_a * A_total
// amode: 0 = plain fp32; 1 = quad (sum 4 slices); 2 = virtual V0 = k2^T * dval
// bmode: 1 = quad; 2 = virtual V0
__global__ __launch_bounds__(256) void ns4_kernel(
    const float* __restrict__ A, int amode,
    const float* __restrict__ B, int bmode,
    const float* __restrict__ denw, float* __restrict__ O,
    float s_a, float s_ab) {
  __shared__ float As[32][68];    // [row][k-quarter], pitch 68 (mod-32 = 4, conflict-free)
  __shared__ float Bs[64][36];    // [k-quarter][col]
  int t = threadIdx.x;
  int bi = blockIdx.y * 32, bj = blockIdx.x * 32;
  int b = blockIdx.z >> 2, slice = blockIdx.z & 3;
  int k0 = slice * 64;
  size_t bo = (size_t)b * NM * NM;
  float dval = (amode == 2 || bmode == 2) ? 1.0f / fmaxf(denw[0], denw[1]) : 0.f;
  // ---- stage A quarter-panel (32 x 64) ----
  if (amode == 2) {
    // As[r][k] = k2[k0+k][bi+r] * dval  (coalesced float4 along r)
    #pragma unroll
    for (int q = 0; q < 2; ++q) {
      int s = q * 256 + t;
      int k = s >> 3, rc = (s & 7) * 4;
      float4 v = *(const float4*)(A + bo + (size_t)(k0 + k) * NM + bi + rc);
      As[rc + 0][k] = v.x * dval; As[rc + 1][k] = v.y * dval;
      As[rc + 2][k] = v.z * dval; As[rc + 3][k] = v.w * dval;
    }
  } else {
    #pragma unroll
    for (int q = 0; q < 2; ++q) {
      int s = q * 256 + t;
      int ar = s >> 4, ac = (s & 15) * 4;
      const float* p = A + bo + (size_t)(bi + ar) * NM + k0 + ac;
      float4 v = *(const float4*)p;
      if (amode == 1) {
        float4 v1 = *(const float4*)(p + SLICE);
        float4 v2 = *(const float4*)(p + 2 * SLICE);
        float4 v3 = *(const float4*)(p + 3 * SLICE);
        v.x += v1.x + v2.x + v3.x; v.y += v1.y + v2.y + v3.y;
        v.z += v1.z + v2.z + v3.z; v.w += v1.w + v2.w + v3.w;
      }
      *(float4*)&As[ar][ac] = v;
    }
  }
  // ---- stage B quarter-panel (64 x 32) ----
  if (bmode == 2) {
    // Bs[k][c] = k2[bj+c][k0+k] * dval  (coalesced float4 along k)
    #pragma unroll
    for (int q = 0; q < 2; ++q) {
      int s = q * 256 + t;
      int c = s >> 4, kc = (s & 15) * 4;
      float4 v = *(const float4*)(B + bo + (size_t)(bj + c) * NM + k0 + kc);
      Bs[kc + 0][c] = v.x * dval; Bs[kc + 1][c] = v.y * dval;
      Bs[kc + 2][c] = v.z * dval; Bs[kc + 3][c] = v.w * dval;
    }
  } else {
    #pragma unroll
    for (int q = 0; q < 2; ++q) {
      int s = q * 256 + t;
      int bk = s >> 3, bc = (s & 7) * 4;
      const float* p = B + bo + (size_t)(k0 + bk) * NM + bj + bc;
      float4 v = *(const float4*)p;
      if (bmode == 1) {
        float4 v1 = *(const float4*)(p + SLICE);
        float4 v2 = *(const float4*)(p + 2 * SLICE);
        float4 v3 = *(const float4*)(p + 3 * SLICE);
        v.x += v1.x + v2.x + v3.x; v.y += v1.y + v2.y + v3.y;
        v.z += v1.z + v2.z + v3.z; v.w += v1.w + v2.w + v3.w;
      }
      *(float4*)&Bs[bk][bc] = v;
    }
  }
  __syncthreads();
  int tx = t & 15, ty = t >> 4;
  float acc[2][2] = {};
  #pragma unroll 8
  for (int kk = 0; kk < 64; ++kk) {
    float a0 = As[ty * 2][kk], a1 = As[ty * 2 + 1][kk];
    float b0 = Bs[kk][tx * 2], b1 = Bs[kk][tx * 2 + 1];
    acc[0][0] += a0 * b0; acc[0][1] += a0 * b1;
    acc[1][0] += a1 * b0; acc[1][1] += a1 * b1;
  }
  float* Op = O + (size_t)slice * SLICE + bo;
  bool addA = (slice == 0) && (s_a != 0.0f);
  #pragma unroll
  for (int i = 0; i < 2; ++i)
    #pragma unroll
    for (int j = 0; j < 2; ++j) {
      int R = bi + ty * 2 + i, C = bj + tx * 2 + j;
      float r = s_ab * acc[i][j];
      if (addA) {
        float av;
        if (amode == 2) {
          av = A[bo + (size_t)C * NM + R] * dval;
        } else if (amode == 1) {
          size_t o = bo + (size_t)R * NM + C;
          av = A[o] + A[o + SLICE] + A[o + 2 * SLICE] + A[o + 3 * SLICE];
        } else {
          av = A[bo + (size_t)R * NM + C];
        }
        r += s_a * av;
      }
      Op[(size_t)R * NM + C] = r;
    }
}

// ---- NS final launch: V' = 3.25*V - 0.25*V@T2 (A,B quads), full K, bf16^T out ----
__global__ __launch_bounds__(256) void gemm_rk32_wt_quad(
    const float* __restrict__ A, const float* __restrict__ Bm,
    ushort* __restrict__ Vt) {
  int b = blockIdx.z;
  int bi = blockIdx.y * 32, bj = blockIdx.x * 32;
  __shared__ float As[32][260];
  __shared__ float Bs[256][36];
  int t = threadIdx.x;
  const float* Ab = A + (size_t)b * NM * NM;
  const float* Bb = Bm + (size_t)b * NM * NM;
  #pragma unroll
  for (int q = 0; q < 8; ++q) {
    int s = q * 256 + t;
    int ar = s >> 6, ac = (s & 63) * 4;
    const float* pa = Ab + (size_t)(bi + ar) * NM + ac;
    float4 va = *(const float4*)pa;
    float4 va1 = *(const float4*)(pa + SLICE);
    float4 va2 = *(const float4*)(pa + 2 * SLICE);
    float4 va3 = *(const float4*)(pa + 3 * SLICE);
    va.x += va1.x + va2.x + va3.x; va.y += va1.y + va2.y + va3.y;
    va.z += va1.z + va2.z + va3.z; va.w += va1.w + va2.w + va3.w;
    *(float4*)&As[ar][ac] = va;
    int br = s >> 3, bc = (s & 7) * 4;
    const float* pb = Bb + (size_t)br * NM + bj + bc;
    float4 vb = *(const float4*)pb;
    float4 vb1 = *(const float4*)(pb + SLICE);
    float4 vb2 = *(const float4*)(pb + 2 * SLICE);
    float4 vb3 = *(const float4*)(pb + 3 * SLICE);
    vb.x += vb1.x + vb2.x + vb3.x; vb.y += vb1.y + vb2.y + vb3.y;
    vb.z += vb1.z + vb2.z + vb3.z; vb.w += vb1.w + vb2.w + vb3.w;
    *(float4*)&Bs[br][bc] = vb;
  }
  __syncthreads();
  int tx = t & 15, ty = t >> 4;
  float acc[2][2] = {};
  #pragma unroll 8
  for (int kk = 0; kk < NM; ++kk) {
    float a0 = As[ty * 2][kk], a1 = As[ty * 2 + 1][kk];
    float b0 = Bs[kk][tx * 2], b1 = Bs[kk][tx * 2 + 1];
    acc[0][0] += a0 * b0; acc[0][1] += a0 * b1;
    acc[1][0] += a1 * b0; acc[1][1] += a1 * b1;
  }
  __syncthreads();
  float (*tile)[33] = (float (*)[33])&As[0][0];
  #pragma unroll
  for (int i = 0; i < 2; ++i)
    #pragma unroll
    for (int j = 0; j < 2; ++j) {
      int R = ty * 2 + i, C = tx * 2 + j;
      size_t o = (size_t)(bi + R) * NM + bj + C;
      float a0v = Ab[o] + Ab[o + SLICE] + Ab[o + 2 * SLICE] + Ab[o + 3 * SLICE];
      tile[R][C] = 3.25f * a0v - 0.25f * acc[i][j];
    }
  __syncthreads();
  int rr = t >> 3, m4 = (t & 7) * 4;
  ushort4 u;
  u.x = f2bf(tile[m4 + 0][rr]); u.y = f2bf(tile[m4 + 1][rr]);
  u.z = f2bf(tile[m4 + 2][rr]); u.w = f2bf(tile[m4 + 3][rr]);
  *(ushort4*)(Vt + ((size_t)b * NM + bj + rr) * NM + bi + m4) = u;
}

// ---------------- k3bf [B][NM][NN] bf16 -> k3t [B][NN][NM] bf16 (transpose) ----------------
__global__ __launch_bounds__(256) void cvt_t_kernel(const ushort* __restrict__ k3,
                                                    ushort* __restrict__ k3t) {
  int b = blockIdx.z;
  int n0 = blockIdx.x * 32, m0 = blockIdx.y * 32;
  __shared__ ushort tile[32][33];
  int t = threadIdx.x;
  int r = t >> 3, c4 = (t & 7) * 4;
  ushort4 v = *(const ushort4*)(k3 + ((size_t)b * NM + m0 + r) * NN + n0 + c4);
  tile[c4][r] = v.x; tile[c4 + 1][r] = v.y; tile[c4 + 2][r] = v.z; tile[c4 + 3][r] = v.w;
  __syncthreads();
  ushort4 u;
  u.x = tile[r][c4];     u.y = tile[r][c4 + 1];
  u.z = tile[r][c4 + 2]; u.w = tile[r][c4 + 3];
  *(ushort4*)(k3t + ((size_t)b * NN + n0 + r) * NM + m0 + c4) = u;
}

// ---------------- A = k1 @ Vinv via bf16 MFMA (R5) ----------------
__global__ __launch_bounds__(256) void gemm_a_mfma(
    const ushort* __restrict__ k1bf, const ushort* __restrict__ Vt,
    ushort* __restrict__ Abf) {
  int b = blockIdx.z;
  int bi = blockIdx.y * 128, bj = blockIdx.x * 128;
  __shared__ ushort As[128 * 64];
  __shared__ ushort Bs[128 * 64];
  int t = threadIdx.x;
  int wave = t >> 6, lane = t & 63;
  int wr = wave >> 1, wc = wave & 1;
  const ushort* Ab = k1bf + (size_t)b * NN * NM;
  const ushort* Bb = Vt + (size_t)b * NM * NM;
  f32x4 acc[4][4] = {};
  for (int k0 = 0; k0 < NM; k0 += 64) {
    #pragma unroll
    for (int q = 0; q < 4; ++q) {
      int s = q * 256 + t;
      int r = s >> 3, c = s & 7;
      int cs = (c ^ (r & 7)) << 3;
      gl_lds16(Ab + (size_t)(bi + r) * NM + k0 + cs, As + (size_t)s * 8);
      gl_lds16(Bb + (size_t)(bj + r) * NM + k0 + cs, Bs + (size_t)s * 8);
    }
    __syncthreads();
    #pragma unroll
    for (int kk = 0; kk < 2; ++kk) {
      int koff = kk * 64 + (lane >> 4) * 16;
      bf16x8 af[4], bfv[4];
      #pragma unroll
      for (int mi = 0; mi < 4; ++mi) {
        int row = wr * 64 + mi * 16 + (lane & 15);
        af[mi] = *(const bf16x8*)((const char*)As + row * 128 + (koff ^ ((row & 7) << 4)));
      }
      #pragma unroll
      for (int nj = 0; nj < 4; ++nj) {
        int row = wc * 64 + nj * 16 + (lane & 15);
        bfv[nj] = *(const bf16x8*)((const char*)Bs + row * 128 + (koff ^ ((row & 7) << 4)));
      }
      #pragma unroll
      for (int mi = 0; mi < 4; ++mi)
        #pragma unroll
        for (int nj = 0; nj < 4; ++nj)
          acc[mi][nj] = __builtin_amdgcn_mfma_f32_16x16x32_bf16(af[mi], bfv[nj], acc[mi][nj], 0, 0, 0);
    }
    __syncthreads();
  }
  int col = lane & 15, rbase = (lane >> 4) * 4;
  #pragma unroll
  for (int mi = 0; mi < 4; ++mi)
    #pragma unroll
    for (int nj = 0; nj < 4; ++nj)
      #pragma unroll
      for (int r = 0; r < 4; ++r)
        Abf[((size_t)b * NN + bi + wr * 64 + mi * 16 + rbase + r) * NM
            + bj + wc * 64 + nj * 16 + col] = f2bf(acc[mi][nj][r]);
}

// ---------------- attn = A @ k3 via bf16 MFMA, 128x128 tile, XCD swizzle, nt stores ----------------
__global__ __launch_bounds__(256) void gemm_attn_mfma(
    const ushort* __restrict__ Abf, const ushort* __restrict__ K3T,
    float* __restrict__ attn) {
  int lin = blockIdx.z * 1024 + blockIdx.y * 32 + blockIdx.x;
  int swz = (lin & 7) * 256 + (lin >> 3);
  int b = swz >> 10;
  int rem = swz & 1023;
  int bi = (rem >> 5) * 128, bj = (rem & 31) * 128;
  __shared__ ushort As[128 * 64];
  __shared__ ushort Bs[128 * 64];
  int t = threadIdx.x;
  int wave = t >> 6, lane = t & 63;
  int wr = wave >> 1, wc = wave & 1;
  const ushort* Ab = Abf + (size_t)b * NN * NM;
  const ushort* Bb = K3T + (size_t)b * NN * NM;
  f32x4 acc[4][4] = {};
  for (int k0 = 0; k0 < NM; k0 += 64) {
    #pragma unroll
    for (int q = 0; q < 4; ++q) {
      int s = q * 256 + t;
      int r = s >> 3, c = s & 7;
      int cs = (c ^ (r & 7)) << 3;
      gl_lds16(Ab + (size_t)(bi + r) * NM + k0 + cs, As + (size_t)s * 8);
      gl_lds16(Bb + (size_t)(bj + r) * NM + k0 + cs, Bs + (size_t)s * 8);
    }
    __syncthreads();
    #pragma unroll
    for (int kk = 0; kk < 2; ++kk) {
      int koff = kk * 64 + (lane >> 4) * 16;
      bf16x8 af[4], bfv[4];
      #pragma unroll
      for (int mi = 0; mi < 4; ++mi) {
        int row = wr * 64 + mi * 16 + (lane & 15);
        af[mi] = *(const bf16x8*)((const char*)As + row * 128 + (koff ^ ((row & 7) << 4)));
      }
      #pragma unroll
      for (int nj = 0; nj < 4; ++nj) {
        int row = wc * 64 + nj * 16 + (lane & 15);
        bfv[nj] = *(const bf16x8*)((const char*)Bs + row * 128 + (koff ^ ((row & 7) << 4)));
      }
      #pragma unroll
      for (int mi = 0; mi < 4; ++mi)
        #pragma unroll
        for (int nj = 0; nj < 4; ++nj)
          acc[mi][nj] = __builtin_amdgcn_mfma_f32_16x16x32_bf16(af[mi], bfv[nj], acc[mi][nj], 0, 0, 0);
    }
    __syncthreads();
  }
  int col = lane & 15, rbase = (lane >> 4) * 4;
  #pragma unroll
  for (int mi = 0; mi < 4; ++mi)
    #pragma unroll
    for (int nj = 0; nj < 4; ++nj)
      #pragma unroll
      for (int r = 0; r < 4; ++r)
        __builtin_nontemporal_store(
            acc[mi][nj][r],
            &attn[((size_t)b * NN + bi + wr * 64 + mi * 16 + rbase + r) * NN
                  + bj + wc * 64 + nj * 16 + col]);
}

// ---------------- split-K kv (k3 bf16, atomicAdd into zeroed buffer) ----------------
__global__ __launch_bounds__(256) void kv_kernel(
    const ushort* __restrict__ K3, const float* __restrict__ Vv,
    float* __restrict__ kvout) {
  int b = blockIdx.z, bp = blockIdx.x * 64;
  int j0base = blockIdx.y * (NN / 32);
  __shared__ float Ks[64][33], Vs[64][33];
  int t = threadIdx.x, tx = t & 15, ty = t >> 4;
  int lrow = t >> 2, ljc = (t & 3) * 8;
  float acc[4][4] = {};
  for (int j0 = j0base; j0 < j0base + NN / 32; j0 += 32) {
    bf16x8 a0 = *(const bf16x8*)(K3 + ((size_t)b * NM + bp + lrow) * NN + j0 + ljc);
    float4 v0 = *(const float4*)(Vv + ((size_t)b * NC + lrow) * NN + j0 + ljc);
    float4 v1 = *(const float4*)(Vv + ((size_t)b * NC + lrow) * NN + j0 + ljc + 4);
    #pragma unroll
    for (int e = 0; e < 8; ++e) Ks[lrow][ljc + e] = bf2f((ushort)a0[e]);
    Vs[lrow][ljc + 0] = v0.x; Vs[lrow][ljc + 1] = v0.y; Vs[lrow][ljc + 2] = v0.z; Vs[lrow][ljc + 3] = v0.w;
    Vs[lrow][ljc + 4] = v1.x; Vs[lrow][ljc + 5] = v1.y; Vs[lrow][ljc + 6] = v1.z; Vs[lrow][ljc + 7] = v1.w;
    __syncthreads();
    #pragma unroll
    for (int kk = 0; kk < 32; ++kk) {
      float av_[4], bv_[4];
      #pragma unroll
      for (int i = 0; i < 4; ++i) av_[i] = Ks[(ty << 2) + i][kk];
      #pragma unroll
      for (int j = 0; j < 4; ++j) bv_[j] = Vs[(tx << 2) + j][kk];
      #pragma unroll
      for (int i = 0; i < 4; ++i)
        #pragma unroll
        for (int j = 0; j < 4; ++j) acc[i][j] += av_[i] * bv_[j];
    }
    __syncthreads();
  }
  #pragma unroll
  for (int i = 0; i < 4; ++i)
    #pragma unroll
    for (int j = 0; j < 4; ++j)
      atomicAdd(&kvout[((size_t)b * NM + bp + (ty << 2) + i) * NC + (tx << 2) + j], acc[i][j]);
}

// ---------------- out = gamma*(A@kv) + x  (A in bf16, nt stores) ----------------
__global__ __launch_bounds__(256) void out_kernel(
    const ushort* __restrict__ Abf, const float* __restrict__ kvm,
    const float* __restrict__ x, const float* __restrict__ gamma,
    float* __restrict__ outp) {
  __shared__ float As[32 * 256];
  int blk = blockIdx.x;
  int b = blk / (NN / 32), n0 = (blk % (NN / 32)) * 32;
  int t = threadIdx.x;
  for (int it = 0; it < 32; ++it)
    As[it * 256 + (t ^ (it & 31))] = bf2f(Abf[((size_t)b * NN + n0 + it) * NM + t]);
  __syncthreads();
  int tn = t & 31, cg0 = (t >> 5) * 8;
  float g = gamma[0];
  float acc[8] = {};
  for (int p = 0; p < NM; ++p) {
    float a = As[tn * 256 + (p ^ (tn & 31))];
    float4 kv0 = *(const float4*)(kvm + ((size_t)b * NM + p) * NC + cg0);
    float4 kv1 = *(const float4*)(kvm + ((size_t)b * NM + p) * NC + cg0 + 4);
    acc[0] += a * kv0.x; acc[1] += a * kv0.y; acc[2] += a * kv0.z; acc[3] += a * kv0.w;
    acc[4] += a * kv1.x; acc[5] += a * kv1.y; acc[6] += a * kv1.z; acc[7] += a * kv1.w;
  }
  #pragma unroll
  for (int qd = 0; qd < 8; ++qd) {
    int c = cg0 + qd;
    size_t idx = ((size_t)b * NC + c) * NN + n0 + tn;
    __builtin_nontemporal_store(g * acc[qd] + x[idx], &outp[idx]);
  }
}

extern "C" void kernel_launch(void* const* d_in, const int* in_sizes, int n_in,
                              void* d_out, int out_size, void* d_ws, size_t ws_size,
                              hipStream_t stream) {
  const float* x     = (const float*)d_in[0];
  const float* wq    = (const float*)d_in[1];
  const float* bq    = (const float*)d_in[2];
  const float* wk    = (const float*)d_in[3];
  const float* bk    = (const float*)d_in[4];
  const float* wv    = (const float*)d_in[5];
  const float* bv    = (const float*)d_in[6];
  const float* gamma = (const float*)d_in[7];
  float* outp = (float*)d_out;                       // [B][C][N]
  float* attn = outp + (size_t)NB * NC * NN;         // [B][N][N]
  float* w = (float*)d_ws;

  float* qw   = w;                 // [B][N][D]    65536
  float* kw   = qw + 65536;        // [B][N][D]    65536
  float* vw   = kw + 65536;        // [B][C][N]    524288
  float* qlw  = vw + 524288;       // [B][M][D]    4096
  float* klw  = qlw + 4096;        // [B][M][D]    4096
  float* k1w  = klw + 4096;        // 8 MB region: k1bf (4MB) + k3T (4MB)
  float* k2w  = k1w + 2097152;     // [B][M][M]    131072
  float* k3w  = k2w + 131072;      // k3bf bf16 row-major (4 MB)
  float* Abuf = k3w + 1048576;     // 4 MB region: Abf bf16
  float* Zp   = Abuf + 1048576;    // quad 524288
  float* T1p  = Zp + 4 * SLICE;    // quad 524288
  float* T2p  = T1p + 4 * SLICE;   // quad 524288
  float* Vap  = T2p + 4 * SLICE;   // quad 524288
  float* Vbp  = Vap + 4 * SLICE;   // quad 524288
  float* Vtw  = Vbp + 4 * SLICE;   // Vinvt bf16   65536 floats
  float* kvw  = Vtw + 65536;       // [B][M][C]    32768
  float* denw = kvw + 32768;       // [2]
  ushort* k1bf  = (ushort*)k1w;                 // [B][N][M] bf16
  ushort* k3T   = (ushort*)k1w + 2097152;       // [B][N][M] bf16 (k3^T)
  ushort* k3bf  = (ushort*)k3w;                 // [B][M][N] bf16 row-major
  ushort* Abf   = (ushort*)Abuf;                // [B][N][M] bf16
  ushort* Vinvt = (ushort*)Vtw;                 // [B][M][M] bf16 (Vinv^T)

  hipMemsetAsync(kvw, 0, (size_t)NB * NM * NC * sizeof(float), stream);
  qkv4_kernel<<<dim3(20, NN / 1024, NB), dim3(256), 0, stream>>>(
      x, wq, bq, wk, bk, wv, bv, qw, kw, vw, qlw, klw);
  scores_all_kernel<<<dim3(2048 + 128 + 512), dim3(256), 0, stream>>>(
      qw, qlw, kw, klw, k1bf, k2w, k3bf);
  denom_kernel<<<dim3(NB), dim3(256), 0, stream>>>(k2w, denw);

  // Newton-Schulz: split-K x4 quads, 1024 blocks/launch (2 per CU).
  // iter 0 (V0 virtual):
  ns4_kernel<<<dim3(8, 8, 4 * NB), dim3(256), 0, stream>>>(k2w, 0, k2w, 2, denw, Zp, 0.f, 1.f);
  ns4_kernel<<<dim3(8, 8, 4 * NB), dim3(256), 0, stream>>>(Zp, 1, Zp, 1, denw, T1p, 7.f, -1.f);
  ns4_kernel<<<dim3(8, 8, 4 * NB), dim3(256), 0, stream>>>(Zp, 1, T1p, 1, denw, T2p, 15.f, -1.f);
  ns4_kernel<<<dim3(8, 8, 4 * NB), dim3(256), 0, stream>>>(k2w, 2, T2p, 1, denw, Vap, 3.25f, -0.25f);
  // iters 1..4:
  float* Vcp = Vap; float* Vnp = Vbp;
  for (int it = 1; it < 5; ++it) {
    ns4_kernel<<<dim3(8, 8, 4 * NB), dim3(256), 0, stream>>>(k2w, 0, Vcp, 1, denw, Zp, 0.f, 1.f);
    ns4_kernel<<<dim3(8, 8, 4 * NB), dim3(256), 0, stream>>>(Zp, 1, Zp, 1, denw, T1p, 7.f, -1.f);
    ns4_kernel<<<dim3(8, 8, 4 * NB), dim3(256), 0, stream>>>(Zp, 1, T1p, 1, denw, T2p, 15.f, -1.f);
    ns4_kernel<<<dim3(8, 8, 4 * NB), dim3(256), 0, stream>>>(Vcp, 1, T2p, 1, denw, Vnp, 3.25f, -0.25f);
    float* tmp = Vcp; Vcp = Vnp; Vnp = tmp;
  }
  // iter 5: final V' -> Vinvt bf16 transposed (full-K quad kernel)
  ns4_kernel<<<dim3(8, 8, 4 * NB), dim3(256), 0, stream>>>(k2w, 0, Vcp, 1, denw, Zp, 0.f, 1.f);
  ns4_kernel<<<dim3(8, 8, 4 * NB), dim3(256), 0, stream>>>(Zp, 1, Zp, 1, denw, T1p, 7.f, -1.f);
  ns4_kernel<<<dim3(8, 8, 4 * NB), dim3(256), 0, stream>>>(Zp, 1, T1p, 1, denw, T2p, 15.f, -1.f);
  gemm_rk32_wt_quad<<<dim3(8, 8, NB), dim3(256), 0, stream>>>(Vcp, T2p, Vinvt);

  cvt_t_kernel<<<dim3(NN / 32, NM / 32, NB), dim3(256), 0, stream>>>(k3bf, k3T);
  gemm_a_mfma<<<dim3(NM / 128, NN / 128, NB), dim3(256), 0, stream>>>(k1bf, Vinvt, Abf);
  gemm_attn_mfma<<<dim3(NN / 128, NN / 128, NB), dim3(256), 0, stream>>>(Abf, k3T, attn);
  kv_kernel<<<dim3(NM / 64, 32, NB), dim3(256), 0, stream>>>(k3bf, vw, kvw);
  out_kernel<<<dim3(NB * NN / 32), dim3(256), 0, stream>>>(Abf, kvw, x, gamma, outp);
}